// Round 5
// baseline (160.147 us; speedup 1.0000x reference)
//
#include <hip/hip_runtime.h>
#include <hip/hip_cooperative_groups.h>
#include <cstdint>
#include <cstddef>

namespace cg = cooperative_groups;

#define NTOT 8192
#define KTOT 256

typedef _Float16 half2v __attribute__((ext_vector_type(2)));
typedef _Float16 half8  __attribute__((ext_vector_type(8)));
typedef float floatx16 __attribute__((ext_vector_type(16)));

// ---- workspace layout (bytes) ----
// G_frag: [k32=8][step=260][lane=64][jj=8] f16  (B-operand, fragment layout)
static constexpr size_t G_ELEMS   = (size_t)8 * 260 * 64 * 8;   // 1,064,960 f16
static constexpr size_t OFF_CK    = G_ELEMS * 2;                // 2,129,920
static constexpr size_t OFF_CNT   = OFF_CK + 1024;
static constexpr size_t OFF_VAL   = 2134016;                    // val2: [8192][4 by][2] f32 = 256 KB

__device__ __forceinline__ uint16_t f2h(float x) {
  _Float16 h = (_Float16)x;
  return __builtin_bit_cast(uint16_t, h);
}

// A-frag: 8 f16 = s2 * rp[0..3]  (4 x v_pk_mul_f16)
__device__ __forceinline__ half8 mkh(half2v s, const half2v* rp) {
  union { half2v p[4]; half8 v; } u;
  u.p[0] = s * rp[0]; u.p[1] = s * rp[1]; u.p[2] = s * rp[2]; u.p[3] = s * rp[3];
  return u.v;
}
__device__ __forceinline__ half8 cph(const half2v* rp) {
  union { half2v p[4]; half8 v; } u;
  u.p[0] = rp[0]; u.p[1] = rp[1]; u.p[2] = rp[2]; u.p[3] = rp[3];
  return u.v;
}

// ---------------- fused: prep -> grid.sync -> GEMM+partial LSE -> last-block reduce
__launch_bounds__(256)
__global__ void fused(const float* __restrict__ x, const float* __restrict__ means,
                      const float* __restrict__ diag, const float* __restrict__ tri,
                      const float* __restrict__ weigh, uint16_t* __restrict__ Gf,
                      float* __restrict__ ck, float* __restrict__ val2,
                      unsigned int* __restrict__ counter, float* __restrict__ out) {
  __shared__ float lv[64], ms[64], bv64[64], wred[256];
  __shared__ float Wp[64][68];   // stride 68: float4-aligned, rotating banks
  __shared__ float SS[64][65];   // stride 65: conflict-free scalar columns
  __shared__ float lse_s;
  __shared__ float xl[128][65];
  __shared__ int ticket_s;

  int t = threadIdx.x;

  // ================= Phase A: per-k prep (k = blockIdx.x) =================
  {
    int k = blockIdx.x;
    if (k == 0 && t == 0) *counter = 0;   // d_ws is re-poisoned each iteration

    // log_softmax denominator over all 256 weights
    float wv = weigh[t];
    wred[t] = wv; __syncthreads();
    for (int o = 128; o > 0; o >>= 1) { if (t < o) wred[t] = fmaxf(wred[t], wred[t + o]); __syncthreads(); }
    float wm = wred[0]; __syncthreads();
    wred[t] = __expf(wv - wm); __syncthreads();
    for (int o = 128; o > 0; o >>= 1) { if (t < o) wred[t] += wred[t + o]; __syncthreads(); }
    if (t == 0) lse_s = wm + __logf(wred[0]);

    float logdet0 = 0.f;   // valid in lane 0 of wave 0 after shuffle
    if (t < 64) {
      float d = diag[k * 64 + t];
      float l = tanhf(d);
      lv[t] = l;
      ms[t] = means[k * 64 + t];
      float ld = __logf(fabsf(l));
      #pragma unroll
      for (int o = 32; o > 0; o >>= 1) ld += __shfl_xor(ld, o);
      logdet0 = ld;
    }
    __syncthreads();

    // build W' = (I + strict_lower(tri)) * diag(lv)
    for (int e = 0; e < 16; ++e) {
      int idx = e * 256 + t;
      int i = idx >> 6, c = idx & 63;
      float L = (c < i) ? tri[k * 4096 + idx] : 0.f;
      float w = ((c == i) ? 1.f : 0.f) + L;
      Wp[i][c] = w * lv[c];
    }
    __syncthreads();

    // S = W'^T W' : each thread a 4x4 tile
    int i0 = (t >> 4) * 4, j0 = (t & 15) * 4;
    float acc[4][4];
    #pragma unroll
    for (int a = 0; a < 4; ++a)
      #pragma unroll
      for (int b = 0; b < 4; ++b) acc[a][b] = 0.f;
    for (int r = 0; r < 64; ++r) {
      float4 av = *(const float4*)&Wp[r][i0];
      float4 bv = *(const float4*)&Wp[r][j0];
      float aa[4] = {av.x, av.y, av.z, av.w};
      float bb[4] = {bv.x, bv.y, bv.z, bv.w};
      #pragma unroll
      for (int a = 0; a < 4; ++a)
        #pragma unroll
        for (int b = 0; b < 4; ++b) acc[a][b] = fmaf(aa[a], bb[b], acc[a][b]);
    }
    #pragma unroll
    for (int a = 0; a < 4; ++a)
      #pragma unroll
      for (int b = 0; b < 4; ++b) SS[i0 + a][j0 + b] = acc[a][b];
    __syncthreads();

    // bv = S m  (conflict-free: SS stride 65), msm via shuffle
    if (t < 64) {
      float b = 0.f;
      for (int j = 0; j < 64; ++j) b = fmaf(SS[t][j], ms[j], b);
      bv64[t] = b;
      float bm = b * ms[t];
      #pragma unroll
      for (int o = 32; o > 0; o >>= 1) bm += __shfl_xor(bm, o);
      if (t == 0) ck[k] = logdet0 + (weigh[k] - lse_s) - 0.5f * bm;
    }
    __syncthreads();

    // Gf stores: 520 x 16B chunks. chunk cc covers features u = 8cc..8cc+7.
    int k32 = k >> 5, kl = k & 31;
    for (int cc = t; cc < 520; cc += 256) {
      float v[8];
      if (cc < 512) {
        int i = cc >> 3, jb = (cc & 7) * 8;
        #pragma unroll
        for (int e = 0; e < 8; ++e) v[e] = -0.5f * SS[i][jb + e];
      } else {
        int b0 = (cc - 512) * 8;
        #pragma unroll
        for (int e = 0; e < 8; ++e) v[e] = bv64[b0 + e];
      }
      uint4 pk;
      pk.x = (uint32_t)f2h(v[0]) | ((uint32_t)f2h(v[1]) << 16);
      pk.y = (uint32_t)f2h(v[2]) | ((uint32_t)f2h(v[3]) << 16);
      pk.z = (uint32_t)f2h(v[4]) | ((uint32_t)f2h(v[5]) << 16);
      pk.w = (uint32_t)f2h(v[6]) | ((uint32_t)f2h(v[7]) << 16);
      size_t base = ((size_t)(k32 * 260 + (cc >> 1)) * 64 + (cc & 1) * 32 + kl) * 8;
      *(uint4*)(Gf + base) = pk;
    }
  }

  // ============ grid-wide barrier (device-scope fence included) ============
  cg::this_grid().sync();

  // ================= Phase B: MFMA GEMM + fused partial LSE ================
  {
    int bx = blockIdx.x >> 2, by = blockIdx.x & 3;  // row-sharing blocks adjacent
    const float* xblk = x + (size_t)bx * (128 * 64);

    for (int e = 0; e < 8; ++e) {
      int lin = e * 1024 + t * 4;
      float4 v = *(const float4*)(xblk + lin);
      int r = lin >> 6, c = lin & 63;
      xl[r][c] = v.x; xl[r][c + 1] = v.y; xl[r][c + 2] = v.z; xl[r][c + 3] = v.w;
    }
    __syncthreads();

    int wave = t >> 6, l = t & 63;
    int wn = wave >> 1, wk = wave & 1;
    int half = l >> 5, lane31 = l & 31;
    int r0 = wn * 64 + lane31, r1 = r0 + 32;

    // per-lane x runs in packed f16: row r, chunks c*16 + half*8 .. +7
    half2v runh0[4][4], runh1[4][4];
    #pragma unroll
    for (int c = 0; c < 4; ++c) {
      int base = c * 16 + half * 8;
      float4 ra = *(const float4*)(xblk + (size_t)r0 * 64 + base);
      float4 rb = *(const float4*)(xblk + (size_t)r0 * 64 + base + 4);
      runh0[c][0][0] = (_Float16)ra.x; runh0[c][0][1] = (_Float16)ra.y;
      runh0[c][1][0] = (_Float16)ra.z; runh0[c][1][1] = (_Float16)ra.w;
      runh0[c][2][0] = (_Float16)rb.x; runh0[c][2][1] = (_Float16)rb.y;
      runh0[c][3][0] = (_Float16)rb.z; runh0[c][3][1] = (_Float16)rb.w;
      float4 rc = *(const float4*)(xblk + (size_t)r1 * 64 + base);
      float4 rd = *(const float4*)(xblk + (size_t)r1 * 64 + base + 4);
      runh1[c][0][0] = (_Float16)rc.x; runh1[c][0][1] = (_Float16)rc.y;
      runh1[c][1][0] = (_Float16)rc.z; runh1[c][1][1] = (_Float16)rc.w;
      runh1[c][2][0] = (_Float16)rd.x; runh1[c][2][1] = (_Float16)rd.y;
      runh1[c][3][0] = (_Float16)rd.z; runh1[c][3][1] = (_Float16)rd.w;
    }

    int k32 = by * 2 + wk;
    const uint4* Bp = (const uint4*)Gf;
    size_t bofs = (size_t)(k32 * 260) * 64 + l;

    floatx16 acc0, acc1;
    #pragma unroll
    for (int i = 0; i < 16; ++i) { acc0[i] = 0.f; acc1[i] = 0.f; }

    // 4-deep prefetch; overruns past step 259 stay inside d_ws (never consumed)
    uint4 bufs[4][4];
    #pragma unroll
    for (int p = 0; p < 4; ++p)
      #pragma unroll
      for (int c = 0; c < 4; ++c) bufs[p][c] = Bp[bofs + (size_t)(p * 4 + c) * 64];

    for (int g = 0; g < 64; g += 4) {
      #pragma unroll
      for (int p = 0; p < 4; ++p) {
        int gg = g + p;
        float xf0 = xl[r0][gg], xf1 = xl[r1][gg];
        _Float16 h0 = (_Float16)xf0; half2v xi0; xi0[0] = h0; xi0[1] = h0;
        _Float16 h1 = (_Float16)xf1; half2v xi1; xi1[0] = h1; xi1[1] = h1;
        #pragma unroll
        for (int c = 0; c < 4; ++c) {
          half8 a0 = mkh(xi0, runh0[c]);
          half8 a1 = mkh(xi1, runh1[c]);
          half8 bb = __builtin_bit_cast(half8, bufs[p][c]);
          acc0 = __builtin_amdgcn_mfma_f32_32x32x16_f16(a0, bb, acc0, 0, 0, 0);
          acc1 = __builtin_amdgcn_mfma_f32_32x32x16_f16(a1, bb, acc1, 0, 0, 0);
        }
        #pragma unroll
        for (int c = 0; c < 4; ++c)
          bufs[p][c] = Bp[bofs + (size_t)((gg + 4) * 4 + c) * 64];
      }
    }

    // tail: steps 256..259 (Sm features, A = raw x) — prefetched in bufs[0]
    #pragma unroll
    for (int c = 0; c < 4; ++c) {
      half8 a0 = cph(runh0[c]);
      half8 a1 = cph(runh1[c]);
      half8 bb = __builtin_bit_cast(half8, bufs[0][c]);
      acc0 = __builtin_amdgcn_mfma_f32_32x32x16_f16(a0, bb, acc0, 0, 0, 0);
      acc1 = __builtin_amdgcn_mfma_f32_32x32x16_f16(a1, bb, acc1, 0, 0, 0);
    }

    // epilogue: stash val (+ck) into xl (reuse), then per-row partial LSE
    __syncthreads();
    float ckv = ck[by * 64 + wk * 32 + lane31];
    #pragma unroll
    for (int reg = 0; reg < 16; ++reg) {
      int row = (reg & 3) + 8 * (reg >> 2) + 4 * half;
      xl[wn * 64 + row][wk * 32 + lane31] = acc0[reg] + ckv;
      xl[wn * 64 + 32 + row][wk * 32 + lane31] = acc1[reg] + ckv;
    }
    __syncthreads();
    if (t < 128) {
      float m = -3.0e38f;
      #pragma unroll
      for (int j = 0; j < 64; ++j) m = fmaxf(m, xl[t][j]);
      float s = 0.f;
      #pragma unroll
      for (int j = 0; j < 64; ++j) s += __expf(xl[t][j] - m);
      size_t n = (size_t)bx * 128 + t;
      val2[n * 8 + by * 2 + 0] = m;
      val2[n * 8 + by * 2 + 1] = s;
    }
    __syncthreads();
  }

  // ============ Phase C: last block combines + writes the scalar ============
  if (t == 0) {
    __threadfence();                       // release val2 writes (device scope)
    ticket_s = (int)atomicAdd(counter, 1u);
  }
  __syncthreads();
  if (ticket_s == 255) {
    __threadfence();                       // acquire all blocks' val2
    float acc = 0.f;
    #pragma unroll 4
    for (int i = 0; i < 32; ++i) {
      size_t n = (size_t)i * 256 + t;
      const float4* p = (const float4*)(val2 + n * 8);
      float4 a = p[0], b = p[1];
      float M = fmaxf(fmaxf(a.x, a.z), fmaxf(b.x, b.z));
      float s = a.y * __expf(a.x - M) + a.w * __expf(a.z - M) +
                b.y * __expf(b.x - M) + b.w * __expf(b.z - M);
      acc += M + __logf(s);
    }
    __syncthreads();
    wred[t] = acc; __syncthreads();
    for (int o = 128; o > 0; o >>= 1) { if (t < o) wred[t] += wred[t + o]; __syncthreads(); }
    if (t == 0) out[0] = 58.8120661251f - wred[0] / 8192.0f;  // 32*log(2pi) - mean(lse)
  }
}

extern "C" void kernel_launch(void* const* d_in, const int* in_sizes, int n_in,
                              void* d_out, int out_size, void* d_ws, size_t ws_size,
                              hipStream_t stream) {
  const float* x     = (const float*)d_in[0];
  const float* means = (const float*)d_in[1];
  const float* diag  = (const float*)d_in[2];
  const float* tri   = (const float*)d_in[3];
  const float* weigh = (const float*)d_in[4];

  char* ws = (char*)d_ws;
  uint16_t* Gf          = (uint16_t*)ws;
  float* ck             = (float*)(ws + OFF_CK);
  unsigned int* counter = (unsigned int*)(ws + OFF_CNT);
  float* val2           = (float*)(ws + OFF_VAL);
  float* out            = (float*)d_out;

  void* args[] = { (void*)&x, (void*)&means, (void*)&diag, (void*)&tri, (void*)&weigh,
                   (void*)&Gf, (void*)&ck, (void*)&val2, (void*)&counter, (void*)&out };
  hipLaunchCooperativeKernel((void*)fused, dim3(256), dim3(256), args, 0, stream);
}